// Round 13
// baseline (1011.529 us; speedup 1.0000x reference)
//
#include <hip/hip_runtime.h>
#include <hip/hip_bf16.h>

typedef __hip_bfloat16 bf16;
typedef __attribute__((ext_vector_type(8))) short short8;
typedef __attribute__((ext_vector_type(4))) float f32x4;

#define ROWS 8192   // B*N
#define NPTS 2048
#define CIN  128
#define COUT 256
#define KNN  32
#define PAD  129    // dist_feat LDS leading dim: stride%32==1 -> conflict-free (was 132: 4-way)

__device__ inline float lrelu(float x){ return x >= 0.f ? x : 0.2f*x; }
__device__ inline unsigned short f2bf(float x){
  bf16 h = __float2bfloat16(x);
  return *(unsigned short*)&h;
}
__device__ inline float bf2f(unsigned short u){ return __uint_as_float((unsigned)u << 16); }
__device__ inline void stc(float* p, float v){ *p = v; }
__device__ inline void stc(unsigned short* p, float v){ *p = f2bf(v); }

// ---------------- fused one-time prep: WT_x, bcat, WT_ffn, WT_fc, feat_bf ----------------
#define N_WTX   (2048*CIN)          // 262144
#define N_WFFN  (2*COUT*COUT)       // 131072
#define N_WFC   (COUT*512)          // 131072
#define N_FEAT  (ROWS*CIN)          // 1048576
__global__ __launch_bounds__(256) void pack_all(
    const float* qW, const float* kW, const float* vW, const float* rW,
    const float* qb, const float* kb, const float* vb, const float* rb,
    const float* ffnW, const float* fcW, const float* feature,
    unsigned short* WT_x, float* bcat, unsigned short* WT_ffn,
    unsigned short* WT_fc, unsigned short* feat_bf){
  int t = blockIdx.x*256 + threadIdx.x;
  if (t < N_WTX){
    int c = t >> 7, r = t & 127;
    int g = c >> 8, i = g >> 2, tt = g & 3, cc = c & 255;
    const float* W = (tt==0?qW: tt==1?kW: tt==2?vW: rW) + (size_t)i*CIN*COUT;
    WT_x[t] = f2bf(W[r*COUT + cc]);
    if (r == 0){
      const float* bb = (tt==0?qb: tt==1?kb: tt==2?vb: rb) + i*COUT;
      bcat[c] = bb[cc];
    }
  } else if (t < N_WTX + N_WFFN){
    int u = t - N_WTX;
    int i = u >> 16, n = (u >> 8) & 255, k = u & 255;
    WT_ffn[u] = f2bf(ffnW[(size_t)i*65536 + k*256 + n]);
  } else if (t < N_WTX + N_WFFN + N_WFC){
    int u = t - N_WTX - N_WFFN;
    int n = u >> 9, k = u & 511;
    WT_fc[u] = f2bf(fcW[(size_t)k*256 + n]);
  } else {
    int u = t - N_WTX - N_WFFN - N_WFC;
    feat_bf[u] = f2bf(feature[u]);
  }
}

// ---------------- wave-parallel top-32: two-level cached tournament, exact u64 (d,idx) order ----------------
__device__ inline unsigned long long dist_key(float d, int m){
  unsigned u = __float_as_uint(d);
  u = (u & 0x80000000u) ? ~u : (u | 0x80000000u);
  return ((unsigned long long)u << 32) | (unsigned)m;
}
__device__ inline unsigned long long umin64(unsigned long long a, unsigned long long b){
  return a < b ? a : b;
}

// clear slot jw (within group base G) and recompute that group's cached min
#define TOPK_GROUP_CASE(G)                                              \
  {                                                                     \
    _Pragma("unroll")                                                   \
    for (int j = 0; j < 8; ++j) if (G*8 + j == jw) k64[G*8 + j] = ~0ull;\
    unsigned long long nm = k64[G*8];                                   \
    _Pragma("unroll")                                                   \
    for (int j = 1; j < 8; ++j) nm = umin64(nm, k64[G*8 + j]);          \
    g[G] = nm;                                                          \
  }

__device__ inline void wave_topk32(unsigned long long* k64, int lane, int* out){
  unsigned long long g[4];
  #pragma unroll
  for (int gi = 0; gi < 4; ++gi){
    unsigned long long m = k64[gi*8];
    #pragma unroll
    for (int j = 1; j < 8; ++j) m = umin64(m, k64[gi*8 + j]);
    g[gi] = m;
  }
  for (int r = 0; r < KNN; ++r){
    unsigned long long m = umin64(umin64(g[0], g[1]), umin64(g[2], g[3]));
    #pragma unroll
    for (int s = 1; s < 64; s <<= 1){
      unsigned long long o = __shfl_xor(m, s, 64);
      m = umin64(o, m);
    }
    int wm = (int)(unsigned)(m & 0xFFFFFFFFu);
    if ((wm & 63) == lane){
      int jw = wm >> 6;             // slot index 0..31
      int gw = jw >> 3;             // group 0..3
      if      (gw == 0) TOPK_GROUP_CASE(0)
      else if (gw == 1) TOPK_GROUP_CASE(1)
      else if (gw == 2) TOPK_GROUP_CASE(2)
      else              TOPK_GROUP_CASE(3)
    }
    if (lane == 0) out[r] = wm;
  }
}

// ---------------- xyz KNN (frozen: numpy-faithful fp32, bit-exact) ----------------
__global__ __launch_bounds__(64) void knn_xyz_kernel(const float* xyz, const float* base, int* idx_out){
  __shared__ float drow[NPTS];
  int bid = blockIdx.x;
  int b = bid >> 11;
  int lane = threadIdx.x;
  float q0 = xyz[(size_t)bid*3+0];
  float q1 = xyz[(size_t)bid*3+1];
  float q2 = xyz[(size_t)bid*3+2];
  float qq = __fadd_rn(__fadd_rn(__fmul_rn(q0,q0), __fmul_rn(q1,q1)), __fmul_rn(q2,q2));
  const float* bb = base + (size_t)b*NPTS*3;
  for (int m = lane; m < NPTS; m += 64){
    float p0 = bb[m*3+0], p1 = bb[m*3+1], p2 = bb[m*3+2];
    float pp = __fadd_rn(__fadd_rn(__fmul_rn(p0,p0), __fmul_rn(p1,p1)), __fmul_rn(p2,p2));
    float dot = __fmul_rn(q0,p0);
    dot = __fadd_rn(dot, __fmul_rn(q1,p1));
    dot = __fadd_rn(dot, __fmul_rn(q2,p2));
    drow[m] = __fsub_rn(__fadd_rn(qq, pp), __fmul_rn(2.f, dot));
  }
  __syncthreads();
  unsigned long long k64[32];
  #pragma unroll
  for (int i = 0; i < 32; ++i){
    int m = i*64 + lane;
    k64[i] = dist_key(drow[m], m);
  }
  wave_topk32(k64, lane, idx_out + (size_t)bid*KNN);
}

// ---------------- feature norms (frozen: numpy AVX512 pairwise) ----------------
__global__ __launch_bounds__(256) void rownorm_kernel(const float* feat, float* nrm){
  int row = blockIdx.x*256 + threadIdx.x;
  const float* f = feat + (size_t)row*CIN;
  float L[16];
  #pragma unroll
  for (int l = 0; l < 16; ++l){
    float x0 = __fmul_rn(f[l],     f[l]);
    float x1 = __fmul_rn(f[16+l],  f[16+l]);
    float x2 = __fmul_rn(f[32+l],  f[32+l]);
    float x3 = __fmul_rn(f[48+l],  f[48+l]);
    float x4 = __fmul_rn(f[64+l],  f[64+l]);
    float x5 = __fmul_rn(f[80+l],  f[80+l]);
    float x6 = __fmul_rn(f[96+l],  f[96+l]);
    float x7 = __fmul_rn(f[112+l], f[112+l]);
    L[l] = __fadd_rn(
        __fadd_rn(__fadd_rn(x0,x1), __fadd_rn(x2,x3)),
        __fadd_rn(__fadd_rn(x4,x5), __fadd_rn(x6,x7)));
  }
  float T2[4];
  #pragma unroll
  for (int i = 0; i < 4; ++i)
    T2[i] = __fadd_rn(__fadd_rn(L[i], L[i+8]), __fadd_rn(L[i+4], L[i+12]));
  nrm[row] = __fadd_rn(__fadd_rn(T2[0], T2[2]), __fadd_rn(T2[1], T2[3]));
}

// ---------------- feature self-distance (frozen arithmetic: numpy einsum AVX512 bit-exact) ----------------
__global__ __launch_bounds__(256) void dist_feat_kernel(const float* fb, const float* nrm, float* D){
  __shared__ float Aq[16*PAD];
  __shared__ float Bm[16*PAD];
  int nb = blockIdx.y*16, mb = blockIdx.x*16;
  int t = threadIdx.x;
  {
    int r = t >> 4, seg = (t & 15) << 3;
    const float* an = fb + (size_t)(nb + r)*CIN + seg;
    const float* bm = fb + (size_t)(mb + r)*CIN + seg;
    #pragma unroll
    for (int j = 0; j < 8; ++j){ Aq[r*PAD + seg + j] = an[j]; Bm[r*PAD + seg + j] = bm[j]; }
  }
  __syncthreads();
  int ty = t >> 4, tx = t & 15;
  const float* qa = &Aq[ty*PAD];
  const float* ma = &Bm[tx*PAD];
  float P[16];
  #pragma unroll
  for (int l = 0; l < 16; ++l) P[l] = __fmul_rn(qa[48+l], ma[48+l]);
  #pragma unroll
  for (int l = 0; l < 16; ++l) P[l] = __fmaf_rn(qa[32+l], ma[32+l], P[l]);
  #pragma unroll
  for (int l = 0; l < 16; ++l) P[l] = __fmaf_rn(qa[16+l], ma[16+l], P[l]);
  #pragma unroll
  for (int l = 0; l < 16; ++l) P[l] = __fmaf_rn(qa[ 0+l], ma[ 0+l], P[l]);
  #pragma unroll
  for (int l = 0; l < 16; ++l) P[l] = __fmaf_rn(qa[112+l], ma[112+l], P[l]);
  #pragma unroll
  for (int l = 0; l < 16; ++l) P[l] = __fmaf_rn(qa[96+l], ma[96+l], P[l]);
  #pragma unroll
  for (int l = 0; l < 16; ++l) P[l] = __fmaf_rn(qa[80+l], ma[80+l], P[l]);
  #pragma unroll
  for (int l = 0; l < 16; ++l) P[l] = __fmaf_rn(qa[64+l], ma[64+l], P[l]);
  float T2[4];
  #pragma unroll
  for (int i = 0; i < 4; ++i)
    T2[i] = __fadd_rn(__fadd_rn(P[i], P[i+8]), __fadd_rn(P[i+4], P[i+12]));
  float dot = __fadd_rn(__fadd_rn(T2[0], T2[2]), __fadd_rn(T2[1], T2[3]));
  int n = nb + ty, m = mb + tx;
  D[(size_t)n*NPTS + m] = __fsub_rn(__fadd_rn(nrm[n], nrm[m]), __fmul_rn(2.f, dot));
}

// ---------------- feature top-k (frozen key semantics) ----------------
__global__ __launch_bounds__(64) void topk_row_kernel(const float* D, int* idx_out){
  int n = blockIdx.x;
  int lane = threadIdx.x;
  const float* src = D + (size_t)n*NPTS;
  unsigned long long k64[32];
  #pragma unroll
  for (int i = 0; i < 32; ++i){
    int m = i*64 + lane;
    k64[i] = dist_key(src[m], m);
  }
  wave_topk32(k64, lane, idx_out + (size_t)n*KNN);
}

// ---------------- MFMA GEMM (batched via grid.z): C = bf16(A)[M,K] @ bf16(B^T)[N,K] + bias ----------------
template<typename CT>
__global__ __launch_bounds__(256) void mfma_gemm(const unsigned short* __restrict__ A,
                                                 const unsigned short* __restrict__ Bt,
                                                 const float* __restrict__ bias,
                                                 CT* __restrict__ C, int N, int K,
                                                 size_t sA, size_t sB, size_t sBias, size_t sC){
  int z = blockIdx.z;
  A += (size_t)z*sA; Bt += (size_t)z*sB; bias += (size_t)z*sBias; C += (size_t)z*sC;
  __shared__ unsigned short As[64*40];
  __shared__ unsigned short Bs[64*40];
  int nb = blockIdx.x*64, mb = blockIdx.y*64;
  int t = threadIdx.x;
  int wave = t >> 6, lane = t & 63;
  int m16 = lane & 15, quad = lane >> 4;
  f32x4 acc[4];
  #pragma unroll
  for (int s = 0; s < 4; ++s) acc[s] = (f32x4){0.f, 0.f, 0.f, 0.f};
  int srow = t >> 2, skseg = (t & 3) << 3;
  for (int kt = 0; kt < K; kt += 32){
    __syncthreads();
    *(uint4*)&As[srow*40 + skseg] = *(const uint4*)&A [(size_t)(mb + srow)*K + kt + skseg];
    *(uint4*)&Bs[srow*40 + skseg] = *(const uint4*)&Bt[(size_t)(nb + srow)*K + kt + skseg];
    __syncthreads();
    short8 a = *(const short8*)&As[(wave*16 + m16)*40 + quad*8];
    #pragma unroll
    for (int s = 0; s < 4; ++s){
      short8 b = *(const short8*)&Bs[(s*16 + m16)*40 + quad*8];
      acc[s] = __builtin_amdgcn_mfma_f32_16x16x32_bf16(a, b, acc[s], 0, 0, 0);
    }
  }
  #pragma unroll
  for (int s = 0; s < 4; ++s){
    int col = nb + s*16 + m16;
    float bv = bias[col];
    #pragma unroll
    for (int r = 0; r < 4; ++r){
      int row = mb + wave*16 + quad*4 + r;
      stc(&C[(size_t)row*N + col], acc[s][r] + bv);
    }
  }
}

// ---------------- attention: bf16 X [8192][2048], both branches via grid.y; ushort2 gathers ----------------
__global__ __launch_bounds__(256) void attn_kernel(const unsigned short* X,
                                                   const int* idx0, const int* idx1,
                                                   unsigned short* ctx){
  int i = blockIdx.y;
  const int* ip = (i == 0 ? idx0 : idx1);
  int local = threadIdx.x & 127;
  int r     = threadIdx.x >> 7;
  int bn    = blockIdx.x*2 + r;
  int b     = bn >> 11;
  __shared__ int jr[2][KNN];
  if (local < KNN) jr[r][local] = (b << 11) + ip[(size_t)bn*KNN + local];
  __syncthreads();
  const ushort2* X2 = (const ushort2*)X;
  size_t boff = (size_t)i*512 + local;
  ushort2 q2 = X2[(size_t)bn*1024 + boff];
  float qx = bf2f(q2.x), qy = bf2f(q2.y);
  float ex[KNN], ey[KNN];
  float mx = -3.4e38f, my = -3.4e38f;
  #pragma unroll
  for (int k = 0; k < KNN; ++k){
    ushort2 k2 = X2[(size_t)jr[r][k]*1024 + boff + 128];
    ex[k] = (qx - bf2f(k2.x)) * 0.0625f;
    ey[k] = (qy - bf2f(k2.y)) * 0.0625f;
    mx = fmaxf(mx, ex[k]);
    my = fmaxf(my, ey[k]);
  }
  float sx = 0.f, sy = 0.f;
  #pragma unroll
  for (int k = 0; k < KNN; ++k){
    sx += __expf(ex[k] - mx);
    sy += __expf(ey[k] - my);
  }
  float ix = 1.f / sx, iy = 1.f / sy;
  float bx = -3.4e38f, by = -3.4e38f;
  #pragma unroll
  for (int k = 0; k < KNN; ++k){
    ushort2 v2 = X2[(size_t)jr[r][k]*1024 + boff + 256];
    float ax = __expf(ex[k] - mx)*ix - 1.0f;
    float ay = __expf(ey[k] - my)*iy - 1.0f;
    bx = fmaxf(bx, ax*bf2f(v2.x));
    by = fmaxf(by, ay*bf2f(v2.y));
  }
  ushort2 o; o.x = f2bf(bx); o.y = f2bf(by);
  ((ushort2*)ctx)[((size_t)i*ROWS + bn)*128 + local] = o;
}

// ---------------- BatchNorm stats (deterministic two-stage, batched over branches) ----------------
__global__ __launch_bounds__(256) void bnx_partial(const unsigned short* X, float* partial){
  int p = blockIdx.x, i = blockIdx.y, c = threadIdx.x;
  const unsigned short* base = X + (size_t)i*1024 + 768 + c;
  float s = 0.f, s2 = 0.f;
  for (int r = 0; r < 256; ++r){
    float v = bf2f(base[(size_t)(p*256 + r)*2048]);
    s += v; s2 += v*v;
  }
  partial[((size_t)i*32 + p)*512 + c]       = s;
  partial[((size_t)i*32 + p)*512 + 256 + c] = s2;
}

__global__ __launch_bounds__(256) void bnf_partial(const unsigned short* F, float* partial){
  int p = blockIdx.x, i = blockIdx.y, c = threadIdx.x;
  const unsigned short* base = F + (size_t)i*ROWS*COUT + c;
  float s = 0.f, s2 = 0.f;
  for (int r = 0; r < 256; ++r){
    float v = bf2f(base[(size_t)(p*256 + r)*COUT]);
    s += v; s2 += v*v;
  }
  partial[((size_t)i*32 + p)*512 + c]       = s;
  partial[((size_t)i*32 + p)*512 + 256 + c] = s2;
}

__global__ __launch_bounds__(256) void bny_partial(const float* Y, float* partial){
  int p = blockIdx.x, c = threadIdx.x;
  float s = 0.f, s2 = 0.f;
  for (int r = 0; r < 256; ++r){
    float v = Y[(size_t)(p*256 + r)*COUT + c];
    s += v; s2 += v*v;
  }
  partial[p*512 + c]       = s;
  partial[p*512 + 256 + c] = s2;
}

__global__ __launch_bounds__(256) void bn_final2(const float* partial, float* stats){
  int i = blockIdx.y, c = threadIdx.x;
  partial += (size_t)i*32*512;
  stats   += (size_t)i*512;
  float s = 0.f, s2 = 0.f;
  for (int p = 0; p < 32; ++p){ s += partial[p*512 + c]; s2 += partial[p*512 + 256 + c]; }
  float mean = s * (1.f/8192.f);
  float var  = s2 * (1.f/8192.f) - mean*mean;   // biased var
  stats[c]       = mean;
  stats[256 + c] = 1.f / sqrtf(var + 1e-5f);
}

// ---------------- m_i = leaky(bn_res(res)) + leaky(bn_ffn(F)) -> Mmat bf16, both branches ----------------
__global__ __launch_bounds__(256) void build_m_kernel(const unsigned short* X, const unsigned short* F,
    const float* stats, const float* gR, const float* bR, const float* gF, const float* bF,
    unsigned short* M){
  int bn = blockIdx.x, c = threadIdx.x;
  #pragma unroll
  for (int i = 0; i < 2; ++i){
    float r  = bf2f(X[(size_t)bn*2048 + i*1024 + 768 + c]);
    float rv = gR[i*COUT+c] * (r - stats[i*512+c]) * stats[i*512+256+c] + bR[i*COUT+c];
    rv = lrelu(rv);
    float f  = bf2f(F[(size_t)i*ROWS*COUT + (size_t)bn*COUT + c]);
    float fv = gF[i*COUT+c] * (f - stats[(2+i)*512+c]) * stats[(2+i)*512+256+c] + bF[i*COUT+c];
    fv = lrelu(fv);
    M[(size_t)bn*512 + i*COUT + c] = f2bf(rv + fv);
  }
}

__global__ __launch_bounds__(256) void final_kernel(const float* Y, const float* stats,
                                                    const float* g, const float* be, float* out){
  int bn = blockIdx.x, c = threadIdx.x;
  float y = Y[(size_t)bn*COUT + c];
  float v = g[c] * (y - stats[c]) * stats[256+c] + be[c];
  out[(size_t)bn*COUT + c] = lrelu(v);
}

extern "C" void kernel_launch(void* const* d_in, const int* in_sizes, int n_in,
                              void* d_out, int out_size, void* d_ws, size_t ws_size,
                              hipStream_t stream){
  const float* xyz      = (const float*)d_in[0];
  const float* base_xyz = (const float*)d_in[1];
  const float* feature  = (const float*)d_in[2];
  const float* qW = (const float*)d_in[3];
  const float* qb = (const float*)d_in[4];
  const float* kW = (const float*)d_in[5];
  const float* kb = (const float*)d_in[6];
  const float* vW = (const float*)d_in[7];
  const float* vb = (const float*)d_in[8];
  const float* rW = (const float*)d_in[9];
  const float* rb = (const float*)d_in[10];
  const float* res_gamma = (const float*)d_in[11];
  const float* res_beta  = (const float*)d_in[12];
  const float* ffnW = (const float*)d_in[13];
  const float* ffnb = (const float*)d_in[14];
  const float* ffn_gamma = (const float*)d_in[15];
  const float* ffn_beta  = (const float*)d_in[16];
  const float* fcW = (const float*)d_in[17];
  const float* fcb = (const float*)d_in[18];
  const float* fc_gamma = (const float*)d_in[19];
  const float* fc_beta  = (const float*)d_in[20];
  float* out = (float*)d_out;

  // ---- workspace plan (~61 MB, region reuse) ----
  char* ws = (char*)d_ws;
  size_t o = 0;
  auto alloc = [&](size_t bytes)->char*{
    char* p = ws + o;
    o += (bytes + 255) & ~(size_t)255;
    return p;
  };
  int*            idx0    = (int*)           alloc((size_t)ROWS*KNN*4);
  int*            idx1    = (int*)           alloc((size_t)ROWS*KNN*4);
  float*          nrm     = (float*)         alloc((size_t)ROWS*4);
  float*          bcat    = (float*)         alloc((size_t)2048*4);
  unsigned short* WT_x    = (unsigned short*)alloc((size_t)2048*CIN*2);
  unsigned short* WT_ffn  = (unsigned short*)alloc((size_t)2*COUT*COUT*2);
  unsigned short* WT_fc   = (unsigned short*)alloc((size_t)COUT*512*2);
  unsigned short* feat_bf = (unsigned short*)alloc((size_t)ROWS*CIN*2);
  float*          stats   = (float*)         alloc((size_t)5*512*4);
  float*          partial = (float*)         alloc((size_t)2*32*512*4);
  char*           R1      = alloc((size_t)ROWS*2048*2);   // 32 MB: Dbuf fp32 (16MB) -> X bf16 [8192][2048]
  char*           R2      = alloc((size_t)ROWS*COUT*4);   //  8 MB: ctx_bf -> Y fp32
  unsigned short* Mmat_bf = (unsigned short*)alloc((size_t)ROWS*512*2);   // 8 MB
  unsigned short* F_bf    = (unsigned short*)alloc((size_t)2*ROWS*COUT*2);// 8 MB
  float*          Dbuf = (float*)R1;
  unsigned short* X_bf = (unsigned short*)R1;
  unsigned short* ctx_bf = (unsigned short*)R2;
  float*          Y    = (float*)R2;

  // one-time prep (fused)
  pack_all<<<(N_WTX+N_WFFN+N_WFC+N_FEAT)/256, 256, 0, stream>>>(
      qW,kW,vW,rW,qb,kb,vb,rb, ffnW, fcW, feature, WT_x, bcat, WT_ffn, WT_fc, feat_bf);

  knn_xyz_kernel<<<ROWS, 64, 0, stream>>>(xyz, base_xyz, idx0);
  rownorm_kernel<<<ROWS/256, 256, 0, stream>>>(feature, nrm);

  // per-batch feature-distance (frozen bit-exact) + wave-parallel top-k
  for (int b = 0; b < 4; ++b){
    const float* fb = feature + (size_t)b*NPTS*CIN;
    dist_feat_kernel<<<dim3(NPTS/16, NPTS/16), 256, 0, stream>>>(
        fb, nrm + (size_t)b*NPTS, Dbuf);
    topk_row_kernel<<<NPTS, 64, 0, stream>>>(Dbuf, idx1 + (size_t)b*NPTS*KNN);
  }

  // X[8192][2048] bf16 = feat_bf @ WT_x^T, both branches in one launch
  mfma_gemm<unsigned short><<<dim3(2048/64, ROWS/64, 1), 256, 0, stream>>>(
      feat_bf, WT_x, bcat, X_bf, 2048, CIN, 0, 0, 0, 0);

  // attention: both branches, one launch
  attn_kernel<<<dim3(ROWS/2, 2), 256, 0, stream>>>(X_bf, idx0, idx1, ctx_bf);

  // res BN stats (both branches)
  bnx_partial<<<dim3(32, 2), 256, 0, stream>>>(X_bf, partial);
  bn_final2<<<dim3(1, 2), 256, 0, stream>>>(partial, stats);          // slots 0,1

  // ffn GEMM: F_bf[i] = ctx_bf[i] @ ffnW_i + ffnb_i  (batched grid.z=2)
  mfma_gemm<unsigned short><<<dim3(COUT/64, ROWS/64, 2), 256, 0, stream>>>(
      ctx_bf, WT_ffn, ffnb, F_bf, COUT, COUT,
      (size_t)ROWS*COUT, (size_t)COUT*COUT, COUT, (size_t)ROWS*COUT);

  bnf_partial<<<dim3(32, 2), 256, 0, stream>>>(F_bf, partial);
  bn_final2<<<dim3(1, 2), 256, 0, stream>>>(partial, stats + 2*512);  // slots 2,3

  build_m_kernel<<<ROWS, 256, 0, stream>>>(X_bf, F_bf, stats,
      res_gamma, res_beta, ffn_gamma, ffn_beta, Mmat_bf);

  // fc: Y = Mmat @ fcW + fcb  (ctx region dead -> Y)
  mfma_gemm<float><<<dim3(COUT/64, ROWS/64, 1), 256, 0, stream>>>(
      Mmat_bf, WT_fc, fcb, Y, COUT, 512, 0, 0, 0, 0);

  bny_partial<<<32, 256, 0, stream>>>(Y, partial);
  bn_final2<<<dim3(1, 1), 256, 0, stream>>>(partial, stats + 4*512);  // slot 4

  final_kernel<<<ROWS, 256, 0, stream>>>(Y, stats + 4*512, fc_gamma, fc_beta, out);
}

// Round 14
// 598.940 us; speedup vs baseline: 1.6889x; 1.6889x over previous
//
#include <hip/hip_runtime.h>
#include <hip/hip_bf16.h>

typedef __hip_bfloat16 bf16;
typedef __attribute__((ext_vector_type(8))) short short8;
typedef __attribute__((ext_vector_type(4))) float f32x4;

#define ROWS 8192   // B*N
#define NPTS 2048
#define CIN  128
#define COUT 256
#define KNN  32
#define PAD  132    // dist_feat LDS leading dim: 16B-aligned rows -> ds_read_b128, 2-way bank overlap (free; m136)
                    // NOTE: PAD=129 regressed (R13): unaligned rows kill b128 -> 4x LDS ops + more conflicts

__device__ inline float lrelu(float x){ return x >= 0.f ? x : 0.2f*x; }
__device__ inline unsigned short f2bf(float x){
  bf16 h = __float2bfloat16(x);
  return *(unsigned short*)&h;
}
__device__ inline float bf2f(unsigned short u){ return __uint_as_float((unsigned)u << 16); }
__device__ inline void stc(float* p, float v){ *p = v; }
__device__ inline void stc(unsigned short* p, float v){ *p = f2bf(v); }

// ---------------- fused one-time prep: WT_x, bcat, WT_ffn, WT_fc, feat_bf ----------------
#define N_WTX   (2048*CIN)          // 262144
#define N_WFFN  (2*COUT*COUT)       // 131072
#define N_WFC   (COUT*512)          // 131072
#define N_FEAT  (ROWS*CIN)          // 1048576
__global__ __launch_bounds__(256) void pack_all(
    const float* qW, const float* kW, const float* vW, const float* rW,
    const float* qb, const float* kb, const float* vb, const float* rb,
    const float* ffnW, const float* fcW, const float* feature,
    unsigned short* WT_x, float* bcat, unsigned short* WT_ffn,
    unsigned short* WT_fc, unsigned short* feat_bf){
  int t = blockIdx.x*256 + threadIdx.x;
  if (t < N_WTX){
    int c = t >> 7, r = t & 127;
    int g = c >> 8, i = g >> 2, tt = g & 3, cc = c & 255;
    const float* W = (tt==0?qW: tt==1?kW: tt==2?vW: rW) + (size_t)i*CIN*COUT;
    WT_x[t] = f2bf(W[r*COUT + cc]);
    if (r == 0){
      const float* bb = (tt==0?qb: tt==1?kb: tt==2?vb: rb) + i*COUT;
      bcat[c] = bb[cc];
    }
  } else if (t < N_WTX + N_WFFN){
    int u = t - N_WTX;
    int i = u >> 16, n = (u >> 8) & 255, k = u & 255;
    WT_ffn[u] = f2bf(ffnW[(size_t)i*65536 + k*256 + n]);
  } else if (t < N_WTX + N_WFFN + N_WFC){
    int u = t - N_WTX - N_WFFN;
    int n = u >> 9, k = u & 511;
    WT_fc[u] = f2bf(fcW[(size_t)k*256 + n]);
  } else {
    int u = t - N_WTX - N_WFFN - N_WFC;
    feat_bf[u] = f2bf(feature[u]);
  }
}

// ---------------- wave-parallel top-32: two-level cached tournament, exact u64 (d,idx) order ----------------
__device__ inline unsigned long long dist_key(float d, int m){
  unsigned u = __float_as_uint(d);
  u = (u & 0x80000000u) ? ~u : (u | 0x80000000u);
  return ((unsigned long long)u << 32) | (unsigned)m;
}
__device__ inline unsigned long long umin64(unsigned long long a, unsigned long long b){
  return a < b ? a : b;
}

// clear slot jw (within group base G) and recompute that group's cached min
#define TOPK_GROUP_CASE(G)                                              \
  {                                                                     \
    _Pragma("unroll")                                                   \
    for (int j = 0; j < 8; ++j) if (G*8 + j == jw) k64[G*8 + j] = ~0ull;\
    unsigned long long nm = k64[G*8];                                   \
    _Pragma("unroll")                                                   \
    for (int j = 1; j < 8; ++j) nm = umin64(nm, k64[G*8 + j]);          \
    g[G] = nm;                                                          \
  }

__device__ inline void wave_topk32(unsigned long long* k64, int lane, int* out){
  unsigned long long g[4];
  #pragma unroll
  for (int gi = 0; gi < 4; ++gi){
    unsigned long long m = k64[gi*8];
    #pragma unroll
    for (int j = 1; j < 8; ++j) m = umin64(m, k64[gi*8 + j]);
    g[gi] = m;
  }
  for (int r = 0; r < KNN; ++r){
    unsigned long long m = umin64(umin64(g[0], g[1]), umin64(g[2], g[3]));
    #pragma unroll
    for (int s = 1; s < 64; s <<= 1){
      unsigned long long o = __shfl_xor(m, s, 64);
      m = umin64(o, m);
    }
    int wm = (int)(unsigned)(m & 0xFFFFFFFFu);
    if ((wm & 63) == lane){
      int jw = wm >> 6;             // slot index 0..31
      int gw = jw >> 3;             // group 0..3
      if      (gw == 0) TOPK_GROUP_CASE(0)
      else if (gw == 1) TOPK_GROUP_CASE(1)
      else if (gw == 2) TOPK_GROUP_CASE(2)
      else              TOPK_GROUP_CASE(3)
    }
    if (lane == 0) out[r] = wm;
  }
}

// ---------------- xyz KNN (frozen: numpy-faithful fp32, bit-exact) ----------------
__global__ __launch_bounds__(64) void knn_xyz_kernel(const float* xyz, const float* base, int* idx_out){
  __shared__ float drow[NPTS];
  int bid = blockIdx.x;
  int b = bid >> 11;
  int lane = threadIdx.x;
  float q0 = xyz[(size_t)bid*3+0];
  float q1 = xyz[(size_t)bid*3+1];
  float q2 = xyz[(size_t)bid*3+2];
  float qq = __fadd_rn(__fadd_rn(__fmul_rn(q0,q0), __fmul_rn(q1,q1)), __fmul_rn(q2,q2));
  const float* bb = base + (size_t)b*NPTS*3;
  for (int m = lane; m < NPTS; m += 64){
    float p0 = bb[m*3+0], p1 = bb[m*3+1], p2 = bb[m*3+2];
    float pp = __fadd_rn(__fadd_rn(__fmul_rn(p0,p0), __fmul_rn(p1,p1)), __fmul_rn(p2,p2));
    float dot = __fmul_rn(q0,p0);
    dot = __fadd_rn(dot, __fmul_rn(q1,p1));
    dot = __fadd_rn(dot, __fmul_rn(q2,p2));
    drow[m] = __fsub_rn(__fadd_rn(qq, pp), __fmul_rn(2.f, dot));
  }
  __syncthreads();
  unsigned long long k64[32];
  #pragma unroll
  for (int i = 0; i < 32; ++i){
    int m = i*64 + lane;
    k64[i] = dist_key(drow[m], m);
  }
  wave_topk32(k64, lane, idx_out + (size_t)bid*KNN);
}

// ---------------- feature norms (frozen: numpy AVX512 pairwise) ----------------
__global__ __launch_bounds__(256) void rownorm_kernel(const float* feat, float* nrm){
  int row = blockIdx.x*256 + threadIdx.x;
  const float* f = feat + (size_t)row*CIN;
  float L[16];
  #pragma unroll
  for (int l = 0; l < 16; ++l){
    float x0 = __fmul_rn(f[l],     f[l]);
    float x1 = __fmul_rn(f[16+l],  f[16+l]);
    float x2 = __fmul_rn(f[32+l],  f[32+l]);
    float x3 = __fmul_rn(f[48+l],  f[48+l]);
    float x4 = __fmul_rn(f[64+l],  f[64+l]);
    float x5 = __fmul_rn(f[80+l],  f[80+l]);
    float x6 = __fmul_rn(f[96+l],  f[96+l]);
    float x7 = __fmul_rn(f[112+l], f[112+l]);
    L[l] = __fadd_rn(
        __fadd_rn(__fadd_rn(x0,x1), __fadd_rn(x2,x3)),
        __fadd_rn(__fadd_rn(x4,x5), __fadd_rn(x6,x7)));
  }
  float T2[4];
  #pragma unroll
  for (int i = 0; i < 4; ++i)
    T2[i] = __fadd_rn(__fadd_rn(L[i], L[i+8]), __fadd_rn(L[i+4], L[i+12]));
  nrm[row] = __fadd_rn(__fadd_rn(T2[0], T2[2]), __fadd_rn(T2[1], T2[3]));
}

// ---------------- feature self-distance (frozen arithmetic: numpy einsum AVX512 bit-exact) ----------------
__global__ __launch_bounds__(256) void dist_feat_kernel(const float* fb, const float* nrm, float* D){
  __shared__ float Aq[16*PAD];
  __shared__ float Bm[16*PAD];
  int nb = blockIdx.y*16, mb = blockIdx.x*16;
  int t = threadIdx.x;
  {
    int r = t >> 4, seg = (t & 15) << 3;
    const float* an = fb + (size_t)(nb + r)*CIN + seg;
    const float* bm = fb + (size_t)(mb + r)*CIN + seg;
    #pragma unroll
    for (int j = 0; j < 8; ++j){ Aq[r*PAD + seg + j] = an[j]; Bm[r*PAD + seg + j] = bm[j]; }
  }
  __syncthreads();
  int ty = t >> 4, tx = t & 15;
  const float* qa = &Aq[ty*PAD];
  const float* ma = &Bm[tx*PAD];
  float P[16];
  #pragma unroll
  for (int l = 0; l < 16; ++l) P[l] = __fmul_rn(qa[48+l], ma[48+l]);
  #pragma unroll
  for (int l = 0; l < 16; ++l) P[l] = __fmaf_rn(qa[32+l], ma[32+l], P[l]);
  #pragma unroll
  for (int l = 0; l < 16; ++l) P[l] = __fmaf_rn(qa[16+l], ma[16+l], P[l]);
  #pragma unroll
  for (int l = 0; l < 16; ++l) P[l] = __fmaf_rn(qa[ 0+l], ma[ 0+l], P[l]);
  #pragma unroll
  for (int l = 0; l < 16; ++l) P[l] = __fmaf_rn(qa[112+l], ma[112+l], P[l]);
  #pragma unroll
  for (int l = 0; l < 16; ++l) P[l] = __fmaf_rn(qa[96+l], ma[96+l], P[l]);
  #pragma unroll
  for (int l = 0; l < 16; ++l) P[l] = __fmaf_rn(qa[80+l], ma[80+l], P[l]);
  #pragma unroll
  for (int l = 0; l < 16; ++l) P[l] = __fmaf_rn(qa[64+l], ma[64+l], P[l]);
  float T2[4];
  #pragma unroll
  for (int i = 0; i < 4; ++i)
    T2[i] = __fadd_rn(__fadd_rn(P[i], P[i+8]), __fadd_rn(P[i+4], P[i+12]));
  float dot = __fadd_rn(__fadd_rn(T2[0], T2[2]), __fadd_rn(T2[1], T2[3]));
  int n = nb + ty, m = mb + tx;
  D[(size_t)n*NPTS + m] = __fsub_rn(__fadd_rn(nrm[n], nrm[m]), __fmul_rn(2.f, dot));
}

// ---------------- feature top-k (frozen key semantics) ----------------
__global__ __launch_bounds__(64) void topk_row_kernel(const float* D, int* idx_out){
  int n = blockIdx.x;
  int lane = threadIdx.x;
  const float* src = D + (size_t)n*NPTS;
  unsigned long long k64[32];
  #pragma unroll
  for (int i = 0; i < 32; ++i){
    int m = i*64 + lane;
    k64[i] = dist_key(src[m], m);
  }
  wave_topk32(k64, lane, idx_out + (size_t)n*KNN);
}

// ---------------- MFMA GEMM (batched via grid.z): C = bf16(A)[M,K] @ bf16(B^T)[N,K] + bias ----------------
template<typename CT>
__global__ __launch_bounds__(256) void mfma_gemm(const unsigned short* __restrict__ A,
                                                 const unsigned short* __restrict__ Bt,
                                                 const float* __restrict__ bias,
                                                 CT* __restrict__ C, int N, int K,
                                                 size_t sA, size_t sB, size_t sBias, size_t sC){
  int z = blockIdx.z;
  A += (size_t)z*sA; Bt += (size_t)z*sB; bias += (size_t)z*sBias; C += (size_t)z*sC;
  __shared__ unsigned short As[64*40];
  __shared__ unsigned short Bs[64*40];
  int nb = blockIdx.x*64, mb = blockIdx.y*64;
  int t = threadIdx.x;
  int wave = t >> 6, lane = t & 63;
  int m16 = lane & 15, quad = lane >> 4;
  f32x4 acc[4];
  #pragma unroll
  for (int s = 0; s < 4; ++s) acc[s] = (f32x4){0.f, 0.f, 0.f, 0.f};
  int srow = t >> 2, skseg = (t & 3) << 3;
  for (int kt = 0; kt < K; kt += 32){
    __syncthreads();
    *(uint4*)&As[srow*40 + skseg] = *(const uint4*)&A [(size_t)(mb + srow)*K + kt + skseg];
    *(uint4*)&Bs[srow*40 + skseg] = *(const uint4*)&Bt[(size_t)(nb + srow)*K + kt + skseg];
    __syncthreads();
    short8 a = *(const short8*)&As[(wave*16 + m16)*40 + quad*8];
    #pragma unroll
    for (int s = 0; s < 4; ++s){
      short8 b = *(const short8*)&Bs[(s*16 + m16)*40 + quad*8];
      acc[s] = __builtin_amdgcn_mfma_f32_16x16x32_bf16(a, b, acc[s], 0, 0, 0);
    }
  }
  #pragma unroll
  for (int s = 0; s < 4; ++s){
    int col = nb + s*16 + m16;
    float bv = bias[col];
    #pragma unroll
    for (int r = 0; r < 4; ++r){
      int row = mb + wave*16 + quad*4 + r;
      stc(&C[(size_t)row*N + col], acc[s][r] + bv);
    }
  }
}

// ---------------- attention: bf16 X [8192][2048], both branches via grid.y; ushort2 gathers ----------------
__global__ __launch_bounds__(256) void attn_kernel(const unsigned short* X,
                                                   const int* idx0, const int* idx1,
                                                   unsigned short* ctx){
  int i = blockIdx.y;
  const int* ip = (i == 0 ? idx0 : idx1);
  int local = threadIdx.x & 127;
  int r     = threadIdx.x >> 7;
  int bn    = blockIdx.x*2 + r;
  int b     = bn >> 11;
  __shared__ int jr[2][KNN];
  if (local < KNN) jr[r][local] = (b << 11) + ip[(size_t)bn*KNN + local];
  __syncthreads();
  const ushort2* X2 = (const ushort2*)X;
  size_t boff = (size_t)i*512 + local;
  ushort2 q2 = X2[(size_t)bn*1024 + boff];
  float qx = bf2f(q2.x), qy = bf2f(q2.y);
  float ex[KNN], ey[KNN];
  float mx = -3.4e38f, my = -3.4e38f;
  #pragma unroll
  for (int k = 0; k < KNN; ++k){
    ushort2 k2 = X2[(size_t)jr[r][k]*1024 + boff + 128];
    ex[k] = (qx - bf2f(k2.x)) * 0.0625f;
    ey[k] = (qy - bf2f(k2.y)) * 0.0625f;
    mx = fmaxf(mx, ex[k]);
    my = fmaxf(my, ey[k]);
  }
  float sx = 0.f, sy = 0.f;
  #pragma unroll
  for (int k = 0; k < KNN; ++k){
    sx += __expf(ex[k] - mx);
    sy += __expf(ey[k] - my);
  }
  float ix = 1.f / sx, iy = 1.f / sy;
  float bx = -3.4e38f, by = -3.4e38f;
  #pragma unroll
  for (int k = 0; k < KNN; ++k){
    ushort2 v2 = X2[(size_t)jr[r][k]*1024 + boff + 256];
    float ax = __expf(ex[k] - mx)*ix - 1.0f;
    float ay = __expf(ey[k] - my)*iy - 1.0f;
    bx = fmaxf(bx, ax*bf2f(v2.x));
    by = fmaxf(by, ay*bf2f(v2.y));
  }
  ushort2 o; o.x = f2bf(bx); o.y = f2bf(by);
  ((ushort2*)ctx)[((size_t)i*ROWS + bn)*128 + local] = o;
}

// ---------------- BatchNorm stats (deterministic two-stage, batched over branches) ----------------
__global__ __launch_bounds__(256) void bnx_partial(const unsigned short* X, float* partial){
  int p = blockIdx.x, i = blockIdx.y, c = threadIdx.x;
  const unsigned short* base = X + (size_t)i*1024 + 768 + c;
  float s = 0.f, s2 = 0.f;
  for (int r = 0; r < 256; ++r){
    float v = bf2f(base[(size_t)(p*256 + r)*2048]);
    s += v; s2 += v*v;
  }
  partial[((size_t)i*32 + p)*512 + c]       = s;
  partial[((size_t)i*32 + p)*512 + 256 + c] = s2;
}

__global__ __launch_bounds__(256) void bnf_partial(const unsigned short* F, float* partial){
  int p = blockIdx.x, i = blockIdx.y, c = threadIdx.x;
  const unsigned short* base = F + (size_t)i*ROWS*COUT + c;
  float s = 0.f, s2 = 0.f;
  for (int r = 0; r < 256; ++r){
    float v = bf2f(base[(size_t)(p*256 + r)*COUT]);
    s += v; s2 += v*v;
  }
  partial[((size_t)i*32 + p)*512 + c]       = s;
  partial[((size_t)i*32 + p)*512 + 256 + c] = s2;
}

__global__ __launch_bounds__(256) void bny_partial(const float* Y, float* partial){
  int p = blockIdx.x, c = threadIdx.x;
  float s = 0.f, s2 = 0.f;
  for (int r = 0; r < 256; ++r){
    float v = Y[(size_t)(p*256 + r)*COUT + c];
    s += v; s2 += v*v;
  }
  partial[p*512 + c]       = s;
  partial[p*512 + 256 + c] = s2;
}

__global__ __launch_bounds__(256) void bn_final2(const float* partial, float* stats){
  int i = blockIdx.y, c = threadIdx.x;
  partial += (size_t)i*32*512;
  stats   += (size_t)i*512;
  float s = 0.f, s2 = 0.f;
  for (int p = 0; p < 32; ++p){ s += partial[p*512 + c]; s2 += partial[p*512 + 256 + c]; }
  float mean = s * (1.f/8192.f);
  float var  = s2 * (1.f/8192.f) - mean*mean;   // biased var
  stats[c]       = mean;
  stats[256 + c] = 1.f / sqrtf(var + 1e-5f);
}

// ---------------- m_i = leaky(bn_res(res)) + leaky(bn_ffn(F)) -> Mmat bf16, both branches ----------------
__global__ __launch_bounds__(256) void build_m_kernel(const unsigned short* X, const unsigned short* F,
    const float* stats, const float* gR, const float* bR, const float* gF, const float* bF,
    unsigned short* M){
  int bn = blockIdx.x, c = threadIdx.x;
  #pragma unroll
  for (int i = 0; i < 2; ++i){
    float r  = bf2f(X[(size_t)bn*2048 + i*1024 + 768 + c]);
    float rv = gR[i*COUT+c] * (r - stats[i*512+c]) * stats[i*512+256+c] + bR[i*COUT+c];
    rv = lrelu(rv);
    float f  = bf2f(F[(size_t)i*ROWS*COUT + (size_t)bn*COUT + c]);
    float fv = gF[i*COUT+c] * (f - stats[(2+i)*512+c]) * stats[(2+i)*512+256+c] + bF[i*COUT+c];
    fv = lrelu(fv);
    M[(size_t)bn*512 + i*COUT + c] = f2bf(rv + fv);
  }
}

__global__ __launch_bounds__(256) void final_kernel(const float* Y, const float* stats,
                                                    const float* g, const float* be, float* out){
  int bn = blockIdx.x, c = threadIdx.x;
  float y = Y[(size_t)bn*COUT + c];
  float v = g[c] * (y - stats[c]) * stats[256+c] + be[c];
  out[(size_t)bn*COUT + c] = lrelu(v);
}

extern "C" void kernel_launch(void* const* d_in, const int* in_sizes, int n_in,
                              void* d_out, int out_size, void* d_ws, size_t ws_size,
                              hipStream_t stream){
  const float* xyz      = (const float*)d_in[0];
  const float* base_xyz = (const float*)d_in[1];
  const float* feature  = (const float*)d_in[2];
  const float* qW = (const float*)d_in[3];
  const float* qb = (const float*)d_in[4];
  const float* kW = (const float*)d_in[5];
  const float* kb = (const float*)d_in[6];
  const float* vW = (const float*)d_in[7];
  const float* vb = (const float*)d_in[8];
  const float* rW = (const float*)d_in[9];
  const float* rb = (const float*)d_in[10];
  const float* res_gamma = (const float*)d_in[11];
  const float* res_beta  = (const float*)d_in[12];
  const float* ffnW = (const float*)d_in[13];
  const float* ffnb = (const float*)d_in[14];
  const float* ffn_gamma = (const float*)d_in[15];
  const float* ffn_beta  = (const float*)d_in[16];
  const float* fcW = (const float*)d_in[17];
  const float* fcb = (const float*)d_in[18];
  const float* fc_gamma = (const float*)d_in[19];
  const float* fc_beta  = (const float*)d_in[20];
  float* out = (float*)d_out;

  // ---- workspace plan (~61 MB, region reuse) ----
  char* ws = (char*)d_ws;
  size_t o = 0;
  auto alloc = [&](size_t bytes)->char*{
    char* p = ws + o;
    o += (bytes + 255) & ~(size_t)255;
    return p;
  };
  int*            idx0    = (int*)           alloc((size_t)ROWS*KNN*4);
  int*            idx1    = (int*)           alloc((size_t)ROWS*KNN*4);
  float*          nrm     = (float*)         alloc((size_t)ROWS*4);
  float*          bcat    = (float*)         alloc((size_t)2048*4);
  unsigned short* WT_x    = (unsigned short*)alloc((size_t)2048*CIN*2);
  unsigned short* WT_ffn  = (unsigned short*)alloc((size_t)2*COUT*COUT*2);
  unsigned short* WT_fc   = (unsigned short*)alloc((size_t)COUT*512*2);
  unsigned short* feat_bf = (unsigned short*)alloc((size_t)ROWS*CIN*2);
  float*          stats   = (float*)         alloc((size_t)5*512*4);
  float*          partial = (float*)         alloc((size_t)2*32*512*4);
  char*           R1      = alloc((size_t)ROWS*2048*2);   // 32 MB: Dbuf fp32 (16MB) -> X bf16 [8192][2048]
  char*           R2      = alloc((size_t)ROWS*COUT*4);   //  8 MB: ctx_bf -> Y fp32
  unsigned short* Mmat_bf = (unsigned short*)alloc((size_t)ROWS*512*2);   // 8 MB
  unsigned short* F_bf    = (unsigned short*)alloc((size_t)2*ROWS*COUT*2);// 8 MB
  float*          Dbuf = (float*)R1;
  unsigned short* X_bf = (unsigned short*)R1;
  unsigned short* ctx_bf = (unsigned short*)R2;
  float*          Y    = (float*)R2;

  // one-time prep (fused)
  pack_all<<<(N_WTX+N_WFFN+N_WFC+N_FEAT)/256, 256, 0, stream>>>(
      qW,kW,vW,rW,qb,kb,vb,rb, ffnW, fcW, feature, WT_x, bcat, WT_ffn, WT_fc, feat_bf);

  knn_xyz_kernel<<<ROWS, 64, 0, stream>>>(xyz, base_xyz, idx0);
  rownorm_kernel<<<ROWS/256, 256, 0, stream>>>(feature, nrm);

  // per-batch feature-distance (frozen bit-exact) + wave-parallel top-k
  for (int b = 0; b < 4; ++b){
    const float* fb = feature + (size_t)b*NPTS*CIN;
    dist_feat_kernel<<<dim3(NPTS/16, NPTS/16), 256, 0, stream>>>(
        fb, nrm + (size_t)b*NPTS, Dbuf);
    topk_row_kernel<<<NPTS, 64, 0, stream>>>(Dbuf, idx1 + (size_t)b*NPTS*KNN);
  }

  // X[8192][2048] bf16 = feat_bf @ WT_x^T, both branches in one launch
  mfma_gemm<unsigned short><<<dim3(2048/64, ROWS/64, 1), 256, 0, stream>>>(
      feat_bf, WT_x, bcat, X_bf, 2048, CIN, 0, 0, 0, 0);

  // attention: both branches, one launch
  attn_kernel<<<dim3(ROWS/2, 2), 256, 0, stream>>>(X_bf, idx0, idx1, ctx_bf);

  // res BN stats (both branches)
  bnx_partial<<<dim3(32, 2), 256, 0, stream>>>(X_bf, partial);
  bn_final2<<<dim3(1, 2), 256, 0, stream>>>(partial, stats);          // slots 0,1

  // ffn GEMM: F_bf[i] = ctx_bf[i] @ ffnW_i + ffnb_i  (batched grid.z=2)
  mfma_gemm<unsigned short><<<dim3(COUT/64, ROWS/64, 2), 256, 0, stream>>>(
      ctx_bf, WT_ffn, ffnb, F_bf, COUT, COUT,
      (size_t)ROWS*COUT, (size_t)COUT*COUT, COUT, (size_t)ROWS*COUT);

  bnf_partial<<<dim3(32, 2), 256, 0, stream>>>(F_bf, partial);
  bn_final2<<<dim3(1, 2), 256, 0, stream>>>(partial, stats + 2*512);  // slots 2,3

  build_m_kernel<<<ROWS, 256, 0, stream>>>(X_bf, F_bf, stats,
      res_gamma, res_beta, ffn_gamma, ffn_beta, Mmat_bf);

  // fc: Y = Mmat @ fcW + fcb  (ctx region dead -> Y)
  mfma_gemm<float><<<dim3(COUT/64, ROWS/64, 1), 256, 0, stream>>>(
      Mmat_bf, WT_fc, fcb, Y, COUT, 512, 0, 0, 0, 0);

  bny_partial<<<32, 256, 0, stream>>>(Y, partial);
  bn_final2<<<dim3(1, 1), 256, 0, stream>>>(partial, stats + 4*512);  // slot 4

  final_kernel<<<ROWS, 256, 0, stream>>>(Y, stats + 4*512, fc_gamma, fc_beta, out);
}

// Round 15
// 548.859 us; speedup vs baseline: 1.8430x; 1.0912x over previous
//
#include <hip/hip_runtime.h>
#include <hip/hip_bf16.h>

typedef __hip_bfloat16 bf16;
typedef __attribute__((ext_vector_type(8))) short short8;
typedef __attribute__((ext_vector_type(4))) float f32x4;

#define ROWS 8192   // B*N
#define NPTS 2048
#define CIN  128
#define COUT 256
#define KNN  32
#define PAD  132    // dist_feat LDS leading dim: 16B-aligned rows -> ds_read_b128 (PAD=129 regressed, R13)

__device__ inline float lrelu(float x){ return x >= 0.f ? x : 0.2f*x; }
__device__ inline unsigned short f2bf(float x){
  bf16 h = __float2bfloat16(x);
  return *(unsigned short*)&h;
}
__device__ inline float bf2f(unsigned short u){ return __uint_as_float((unsigned)u << 16); }
__device__ inline void stc(float* p, float v){ *p = v; }
__device__ inline void stc(unsigned short* p, float v){ *p = f2bf(v); }

// ---------------- fused one-time prep: WT_x, bcat, WT_ffn, WT_fc, feat_bf ----------------
#define N_WTX   (2048*CIN)          // 262144
#define N_WFFN  (2*COUT*COUT)       // 131072
#define N_WFC   (COUT*512)          // 131072
#define N_FEAT  (ROWS*CIN)          // 1048576
__global__ __launch_bounds__(256) void pack_all(
    const float* qW, const float* kW, const float* vW, const float* rW,
    const float* qb, const float* kb, const float* vb, const float* rb,
    const float* ffnW, const float* fcW, const float* feature,
    unsigned short* WT_x, float* bcat, unsigned short* WT_ffn,
    unsigned short* WT_fc, unsigned short* feat_bf){
  int t = blockIdx.x*256 + threadIdx.x;
  if (t < N_WTX){
    int c = t >> 7, r = t & 127;
    int g = c >> 8, i = g >> 2, tt = g & 3, cc = c & 255;
    const float* W = (tt==0?qW: tt==1?kW: tt==2?vW: rW) + (size_t)i*CIN*COUT;
    WT_x[t] = f2bf(W[r*COUT + cc]);
    if (r == 0){
      const float* bb = (tt==0?qb: tt==1?kb: tt==2?vb: rb) + i*COUT;
      bcat[c] = bb[cc];
    }
  } else if (t < N_WTX + N_WFFN){
    int u = t - N_WTX;
    int i = u >> 16, n = (u >> 8) & 255, k = u & 255;
    WT_ffn[u] = f2bf(ffnW[(size_t)i*65536 + k*256 + n]);
  } else if (t < N_WTX + N_WFFN + N_WFC){
    int u = t - N_WTX - N_WFFN;
    int n = u >> 9, k = u & 511;
    WT_fc[u] = f2bf(fcW[(size_t)k*256 + n]);
  } else {
    int u = t - N_WTX - N_WFFN - N_WFC;
    feat_bf[u] = f2bf(feature[u]);
  }
}

// ---------------- wave-parallel top-32: two-level cached tournament, exact u64 (d,idx) order ----------------
// MODE 0: m = slot*64 + lane  (owner = m&63,  slot = m>>6)
// MODE 1: m = lane*32 + slot  (owner = m>>5,  slot = m&31)
// Selection = global min over all 64x32 keys each round -> output independent of mapping.
__device__ inline unsigned long long dist_key(float d, int m){
  unsigned u = __float_as_uint(d);
  u = (u & 0x80000000u) ? ~u : (u | 0x80000000u);
  return ((unsigned long long)u << 32) | (unsigned)m;
}
__device__ inline unsigned long long umin64(unsigned long long a, unsigned long long b){
  return a < b ? a : b;
}

#define TOPK_GROUP_CASE(G)                                              \
  {                                                                     \
    _Pragma("unroll")                                                   \
    for (int j = 0; j < 8; ++j) if (G*8 + j == jw) k64[G*8 + j] = ~0ull;\
    unsigned long long nm = k64[G*8];                                   \
    _Pragma("unroll")                                                   \
    for (int j = 1; j < 8; ++j) nm = umin64(nm, k64[G*8 + j]);          \
    g[G] = nm;                                                          \
  }

template<int MODE>
__device__ inline void wave_topk32(unsigned long long* k64, int lane, int* out){
  unsigned long long g[4];
  #pragma unroll
  for (int gi = 0; gi < 4; ++gi){
    unsigned long long m = k64[gi*8];
    #pragma unroll
    for (int j = 1; j < 8; ++j) m = umin64(m, k64[gi*8 + j]);
    g[gi] = m;
  }
  for (int r = 0; r < KNN; ++r){
    unsigned long long m = umin64(umin64(g[0], g[1]), umin64(g[2], g[3]));
    #pragma unroll
    for (int s = 1; s < 64; s <<= 1){
      unsigned long long o = __shfl_xor(m, s, 64);
      m = umin64(o, m);
    }
    int wm = (int)(unsigned)(m & 0xFFFFFFFFu);
    int owner = (MODE == 0) ? (wm & 63) : (wm >> 5);
    if (owner == lane){
      int jw = (MODE == 0) ? (wm >> 6) : (wm & 31);
      int gw = jw >> 3;
      if      (gw == 0) TOPK_GROUP_CASE(0)
      else if (gw == 1) TOPK_GROUP_CASE(1)
      else if (gw == 2) TOPK_GROUP_CASE(2)
      else              TOPK_GROUP_CASE(3)
    }
    if (lane == 0) out[r] = wm;
  }
}

// ---------------- xyz KNN (frozen: numpy-faithful fp32, bit-exact) ----------------
__global__ __launch_bounds__(64) void knn_xyz_kernel(const float* xyz, const float* base, int* idx_out){
  __shared__ float drow[NPTS];
  int bid = blockIdx.x;
  int b = bid >> 11;
  int lane = threadIdx.x;
  float q0 = xyz[(size_t)bid*3+0];
  float q1 = xyz[(size_t)bid*3+1];
  float q2 = xyz[(size_t)bid*3+2];
  float qq = __fadd_rn(__fadd_rn(__fmul_rn(q0,q0), __fmul_rn(q1,q1)), __fmul_rn(q2,q2));
  const float* bb = base + (size_t)b*NPTS*3;
  for (int m = lane; m < NPTS; m += 64){
    float p0 = bb[m*3+0], p1 = bb[m*3+1], p2 = bb[m*3+2];
    float pp = __fadd_rn(__fadd_rn(__fmul_rn(p0,p0), __fmul_rn(p1,p1)), __fmul_rn(p2,p2));
    float dot = __fmul_rn(q0,p0);
    dot = __fadd_rn(dot, __fmul_rn(q1,p1));
    dot = __fadd_rn(dot, __fmul_rn(q2,p2));
    drow[m] = __fsub_rn(__fadd_rn(qq, pp), __fmul_rn(2.f, dot));
  }
  __syncthreads();
  unsigned long long k64[32];
  #pragma unroll
  for (int i = 0; i < 32; ++i){
    int m = i*64 + lane;
    k64[i] = dist_key(drow[m], m);
  }
  wave_topk32<0>(k64, lane, idx_out + (size_t)bid*KNN);
}

// ---------------- feature norms (frozen: numpy AVX512 pairwise) ----------------
__global__ __launch_bounds__(256) void rownorm_kernel(const float* feat, float* nrm){
  int row = blockIdx.x*256 + threadIdx.x;
  const float* f = feat + (size_t)row*CIN;
  float L[16];
  #pragma unroll
  for (int l = 0; l < 16; ++l){
    float x0 = __fmul_rn(f[l],     f[l]);
    float x1 = __fmul_rn(f[16+l],  f[16+l]);
    float x2 = __fmul_rn(f[32+l],  f[32+l]);
    float x3 = __fmul_rn(f[48+l],  f[48+l]);
    float x4 = __fmul_rn(f[64+l],  f[64+l]);
    float x5 = __fmul_rn(f[80+l],  f[80+l]);
    float x6 = __fmul_rn(f[96+l],  f[96+l]);
    float x7 = __fmul_rn(f[112+l], f[112+l]);
    L[l] = __fadd_rn(
        __fadd_rn(__fadd_rn(x0,x1), __fadd_rn(x2,x3)),
        __fadd_rn(__fadd_rn(x4,x5), __fadd_rn(x6,x7)));
  }
  float T2[4];
  #pragma unroll
  for (int i = 0; i < 4; ++i)
    T2[i] = __fadd_rn(__fadd_rn(L[i], L[i+8]), __fadd_rn(L[i+4], L[i+12]));
  nrm[row] = __fadd_rn(__fadd_rn(T2[0], T2[2]), __fadd_rn(T2[1], T2[3]));
}

// ---------------- feature self-distance: 32x32 tile, 2x2 outputs/thread (rows ty,ty+16 x cols tx,tx+16)
// Per-output FMA chain identical to numpy einsum AVX512 (frozen, bit-exact).
// Row mapping +16 keeps LDS bank spacing at 4 (2-way overlap = free); {2t,2t+1} would be 4-way.
__global__ __launch_bounds__(256) void dist_feat_kernel(const float* fb, const float* nrm, float* D){
  __shared__ float Aq[32*PAD];
  __shared__ float Bm[32*PAD];
  int nb = blockIdx.y*32, mb = blockIdx.x*32;
  int t = threadIdx.x;
  {
    int r = t >> 3, c16 = (t & 7) << 4;
    const float* an = fb + (size_t)(nb + r)*CIN + c16;
    const float* bm = fb + (size_t)(mb + r)*CIN + c16;
    #pragma unroll
    for (int j = 0; j < 4; ++j){
      *(float4*)&Aq[r*PAD + c16 + 4*j] = *(const float4*)&an[4*j];
      *(float4*)&Bm[r*PAD + c16 + 4*j] = *(const float4*)&bm[4*j];
    }
  }
  __syncthreads();
  int tx = t & 15, ty = t >> 4;
  const float* qa0 = &Aq[(ty     )*PAD];
  const float* qa1 = &Aq[(ty + 16)*PAD];
  const float* ma0 = &Bm[(tx     )*PAD];
  const float* ma1 = &Bm[(tx + 16)*PAD];
  float P[2][2][16];
  // chain order over segments: 48,32,16,0,112,96,80,64 (first = mul)
  #pragma unroll
  for (int l = 0; l < 16; ++l){
    float a0 = qa0[48+l], a1 = qa1[48+l], b0 = ma0[48+l], b1 = ma1[48+l];
    P[0][0][l] = __fmul_rn(a0,b0); P[0][1][l] = __fmul_rn(a0,b1);
    P[1][0][l] = __fmul_rn(a1,b0); P[1][1][l] = __fmul_rn(a1,b1);
  }
  const int segs[7] = {32,16,0,112,96,80,64};
  #pragma unroll
  for (int s = 0; s < 7; ++s){
    int off = segs[s];
    #pragma unroll
    for (int l = 0; l < 16; ++l){
      float a0 = qa0[off+l], a1 = qa1[off+l], b0 = ma0[off+l], b1 = ma1[off+l];
      P[0][0][l] = __fmaf_rn(a0,b0,P[0][0][l]); P[0][1][l] = __fmaf_rn(a0,b1,P[0][1][l]);
      P[1][0][l] = __fmaf_rn(a1,b0,P[1][0][l]); P[1][1][l] = __fmaf_rn(a1,b1,P[1][1][l]);
    }
  }
  #pragma unroll
  for (int i = 0; i < 2; ++i){
    int n = nb + ty + 16*i;
    float nn = nrm[n];
    #pragma unroll
    for (int j = 0; j < 2; ++j){
      float T2[4];
      #pragma unroll
      for (int q = 0; q < 4; ++q)
        T2[q] = __fadd_rn(__fadd_rn(P[i][j][q], P[i][j][q+8]), __fadd_rn(P[i][j][q+4], P[i][j][q+12]));
      float dot = __fadd_rn(__fadd_rn(T2[0], T2[2]), __fadd_rn(T2[1], T2[3]));
      int m = mb + tx + 16*j;
      D[(size_t)n*NPTS + m] = __fsub_rn(__fadd_rn(nn, nrm[m]), __fmul_rn(2.f, dot));
    }
  }
}

// ---------------- feature top-k: float4 loads, slot remap m = lane*32 + j (set-equivalent) ----------------
__global__ __launch_bounds__(64) void topk_row_kernel(const float* D, int* idx_out){
  int n = blockIdx.x;
  int lane = threadIdx.x;
  const float* src = D + (size_t)n*NPTS + lane*32;
  unsigned long long k64[32];
  #pragma unroll
  for (int i = 0; i < 8; ++i){
    float4 v = *(const float4*)&src[i*4];
    int mb = lane*32 + i*4;
    k64[i*4+0] = dist_key(v.x, mb+0);
    k64[i*4+1] = dist_key(v.y, mb+1);
    k64[i*4+2] = dist_key(v.z, mb+2);
    k64[i*4+3] = dist_key(v.w, mb+3);
  }
  wave_topk32<1>(k64, lane, idx_out + (size_t)n*KNN);
}

// ---------------- MFMA GEMM (batched via grid.z): C = bf16(A)[M,K] @ bf16(B^T)[N,K] + bias ----------------
template<typename CT>
__global__ __launch_bounds__(256) void mfma_gemm(const unsigned short* __restrict__ A,
                                                 const unsigned short* __restrict__ Bt,
                                                 const float* __restrict__ bias,
                                                 CT* __restrict__ C, int N, int K,
                                                 size_t sA, size_t sB, size_t sBias, size_t sC){
  int z = blockIdx.z;
  A += (size_t)z*sA; Bt += (size_t)z*sB; bias += (size_t)z*sBias; C += (size_t)z*sC;
  __shared__ unsigned short As[64*40];
  __shared__ unsigned short Bs[64*40];
  int nb = blockIdx.x*64, mb = blockIdx.y*64;
  int t = threadIdx.x;
  int wave = t >> 6, lane = t & 63;
  int m16 = lane & 15, quad = lane >> 4;
  f32x4 acc[4];
  #pragma unroll
  for (int s = 0; s < 4; ++s) acc[s] = (f32x4){0.f, 0.f, 0.f, 0.f};
  int srow = t >> 2, skseg = (t & 3) << 3;
  for (int kt = 0; kt < K; kt += 32){
    __syncthreads();
    *(uint4*)&As[srow*40 + skseg] = *(const uint4*)&A [(size_t)(mb + srow)*K + kt + skseg];
    *(uint4*)&Bs[srow*40 + skseg] = *(const uint4*)&Bt[(size_t)(nb + srow)*K + kt + skseg];
    __syncthreads();
    short8 a = *(const short8*)&As[(wave*16 + m16)*40 + quad*8];
    #pragma unroll
    for (int s = 0; s < 4; ++s){
      short8 b = *(const short8*)&Bs[(s*16 + m16)*40 + quad*8];
      acc[s] = __builtin_amdgcn_mfma_f32_16x16x32_bf16(a, b, acc[s], 0, 0, 0);
    }
  }
  #pragma unroll
  for (int s = 0; s < 4; ++s){
    int col = nb + s*16 + m16;
    float bv = bias[col];
    #pragma unroll
    for (int r = 0; r < 4; ++r){
      int row = mb + wave*16 + quad*4 + r;
      stc(&C[(size_t)row*N + col], acc[s][r] + bv);
    }
  }
}

// ---------------- attention: bf16 X [8192][2048], both branches via grid.y; ushort2 gathers ----------------
__global__ __launch_bounds__(256) void attn_kernel(const unsigned short* X,
                                                   const int* idx0, const int* idx1,
                                                   unsigned short* ctx){
  int i = blockIdx.y;
  const int* ip = (i == 0 ? idx0 : idx1);
  int local = threadIdx.x & 127;
  int r     = threadIdx.x >> 7;
  int bn    = blockIdx.x*2 + r;
  int b     = bn >> 11;
  __shared__ int jr[2][KNN];
  if (local < KNN) jr[r][local] = (b << 11) + ip[(size_t)bn*KNN + local];
  __syncthreads();
  const ushort2* X2 = (const ushort2*)X;
  size_t boff = (size_t)i*512 + local;
  ushort2 q2 = X2[(size_t)bn*1024 + boff];
  float qx = bf2f(q2.x), qy = bf2f(q2.y);
  float ex[KNN], ey[KNN];
  float mx = -3.4e38f, my = -3.4e38f;
  #pragma unroll
  for (int k = 0; k < KNN; ++k){
    ushort2 k2 = X2[(size_t)jr[r][k]*1024 + boff + 128];
    ex[k] = (qx - bf2f(k2.x)) * 0.0625f;
    ey[k] = (qy - bf2f(k2.y)) * 0.0625f;
    mx = fmaxf(mx, ex[k]);
    my = fmaxf(my, ey[k]);
  }
  float sx = 0.f, sy = 0.f;
  #pragma unroll
  for (int k = 0; k < KNN; ++k){
    sx += __expf(ex[k] - mx);
    sy += __expf(ey[k] - my);
  }
  float ix = 1.f / sx, iy = 1.f / sy;
  float bx = -3.4e38f, by = -3.4e38f;
  #pragma unroll
  for (int k = 0; k < KNN; ++k){
    ushort2 v2 = X2[(size_t)jr[r][k]*1024 + boff + 256];
    float ax = __expf(ex[k] - mx)*ix - 1.0f;
    float ay = __expf(ey[k] - my)*iy - 1.0f;
    bx = fmaxf(bx, ax*bf2f(v2.x));
    by = fmaxf(by, ay*bf2f(v2.y));
  }
  ushort2 o; o.x = f2bf(bx); o.y = f2bf(by);
  ((ushort2*)ctx)[((size_t)i*ROWS + bn)*128 + local] = o;
}

// ---------------- BatchNorm stats (deterministic two-stage, batched over branches) ----------------
__global__ __launch_bounds__(256) void bnx_partial(const unsigned short* X, float* partial){
  int p = blockIdx.x, i = blockIdx.y, c = threadIdx.x;
  const unsigned short* base = X + (size_t)i*1024 + 768 + c;
  float s = 0.f, s2 = 0.f;
  for (int r = 0; r < 256; ++r){
    float v = bf2f(base[(size_t)(p*256 + r)*2048]);
    s += v; s2 += v*v;
  }
  partial[((size_t)i*32 + p)*512 + c]       = s;
  partial[((size_t)i*32 + p)*512 + 256 + c] = s2;
}

__global__ __launch_bounds__(256) void bnf_partial(const unsigned short* F, float* partial){
  int p = blockIdx.x, i = blockIdx.y, c = threadIdx.x;
  const unsigned short* base = F + (size_t)i*ROWS*COUT + c;
  float s = 0.f, s2 = 0.f;
  for (int r = 0; r < 256; ++r){
    float v = bf2f(base[(size_t)(p*256 + r)*COUT]);
    s += v; s2 += v*v;
  }
  partial[((size_t)i*32 + p)*512 + c]       = s;
  partial[((size_t)i*32 + p)*512 + 256 + c] = s2;
}

__global__ __launch_bounds__(256) void bny_partial(const float* Y, float* partial){
  int p = blockIdx.x, c = threadIdx.x;
  float s = 0.f, s2 = 0.f;
  for (int r = 0; r < 256; ++r){
    float v = Y[(size_t)(p*256 + r)*COUT + c];
    s += v; s2 += v*v;
  }
  partial[p*512 + c]       = s;
  partial[p*512 + 256 + c] = s2;
}

__global__ __launch_bounds__(256) void bn_final2(const float* partial, float* stats){
  int i = blockIdx.y, c = threadIdx.x;
  partial += (size_t)i*32*512;
  stats   += (size_t)i*512;
  float s = 0.f, s2 = 0.f;
  for (int p = 0; p < 32; ++p){ s += partial[p*512 + c]; s2 += partial[p*512 + 256 + c]; }
  float mean = s * (1.f/8192.f);
  float var  = s2 * (1.f/8192.f) - mean*mean;   // biased var
  stats[c]       = mean;
  stats[256 + c] = 1.f / sqrtf(var + 1e-5f);
}

// ---------------- m_i = leaky(bn_res(res)) + leaky(bn_ffn(F)) -> Mmat bf16, both branches ----------------
__global__ __launch_bounds__(256) void build_m_kernel(const unsigned short* X, const unsigned short* F,
    const float* stats, const float* gR, const float* bR, const float* gF, const float* bF,
    unsigned short* M){
  int bn = blockIdx.x, c = threadIdx.x;
  #pragma unroll
  for (int i = 0; i < 2; ++i){
    float r  = bf2f(X[(size_t)bn*2048 + i*1024 + 768 + c]);
    float rv = gR[i*COUT+c] * (r - stats[i*512+c]) * stats[i*512+256+c] + bR[i*COUT+c];
    rv = lrelu(rv);
    float f  = bf2f(F[(size_t)i*ROWS*COUT + (size_t)bn*COUT + c]);
    float fv = gF[i*COUT+c] * (f - stats[(2+i)*512+c]) * stats[(2+i)*512+256+c] + bF[i*COUT+c];
    fv = lrelu(fv);
    M[(size_t)bn*512 + i*COUT + c] = f2bf(rv + fv);
  }
}

__global__ __launch_bounds__(256) void final_kernel(const float* Y, const float* stats,
                                                    const float* g, const float* be, float* out){
  int bn = blockIdx.x, c = threadIdx.x;
  float y = Y[(size_t)bn*COUT + c];
  float v = g[c] * (y - stats[c]) * stats[256+c] + be[c];
  out[(size_t)bn*COUT + c] = lrelu(v);
}

extern "C" void kernel_launch(void* const* d_in, const int* in_sizes, int n_in,
                              void* d_out, int out_size, void* d_ws, size_t ws_size,
                              hipStream_t stream){
  const float* xyz      = (const float*)d_in[0];
  const float* base_xyz = (const float*)d_in[1];
  const float* feature  = (const float*)d_in[2];
  const float* qW = (const float*)d_in[3];
  const float* qb = (const float*)d_in[4];
  const float* kW = (const float*)d_in[5];
  const float* kb = (const float*)d_in[6];
  const float* vW = (const float*)d_in[7];
  const float* vb = (const float*)d_in[8];
  const float* rW = (const float*)d_in[9];
  const float* rb = (const float*)d_in[10];
  const float* res_gamma = (const float*)d_in[11];
  const float* res_beta  = (const float*)d_in[12];
  const float* ffnW = (const float*)d_in[13];
  const float* ffnb = (const float*)d_in[14];
  const float* ffn_gamma = (const float*)d_in[15];
  const float* ffn_beta  = (const float*)d_in[16];
  const float* fcW = (const float*)d_in[17];
  const float* fcb = (const float*)d_in[18];
  const float* fc_gamma = (const float*)d_in[19];
  const float* fc_beta  = (const float*)d_in[20];
  float* out = (float*)d_out;

  // ---- workspace plan (~61 MB, region reuse) ----
  char* ws = (char*)d_ws;
  size_t o = 0;
  auto alloc = [&](size_t bytes)->char*{
    char* p = ws + o;
    o += (bytes + 255) & ~(size_t)255;
    return p;
  };
  int*            idx0    = (int*)           alloc((size_t)ROWS*KNN*4);
  int*            idx1    = (int*)           alloc((size_t)ROWS*KNN*4);
  float*          nrm     = (float*)         alloc((size_t)ROWS*4);
  float*          bcat    = (float*)         alloc((size_t)2048*4);
  unsigned short* WT_x    = (unsigned short*)alloc((size_t)2048*CIN*2);
  unsigned short* WT_ffn  = (unsigned short*)alloc((size_t)2*COUT*COUT*2);
  unsigned short* WT_fc   = (unsigned short*)alloc((size_t)COUT*512*2);
  unsigned short* feat_bf = (unsigned short*)alloc((size_t)ROWS*CIN*2);
  float*          stats   = (float*)         alloc((size_t)5*512*4);
  float*          partial = (float*)         alloc((size_t)2*32*512*4);
  char*           R1      = alloc((size_t)ROWS*2048*2);   // 32 MB: Dbuf fp32 (16MB) -> X bf16 [8192][2048]
  char*           R2      = alloc((size_t)ROWS*COUT*4);   //  8 MB: ctx_bf -> Y fp32
  unsigned short* Mmat_bf = (unsigned short*)alloc((size_t)ROWS*512*2);   // 8 MB
  unsigned short* F_bf    = (unsigned short*)alloc((size_t)2*ROWS*COUT*2);// 8 MB
  float*          Dbuf = (float*)R1;
  unsigned short* X_bf = (unsigned short*)R1;
  unsigned short* ctx_bf = (unsigned short*)R2;
  float*          Y    = (float*)R2;

  // one-time prep (fused)
  pack_all<<<(N_WTX+N_WFFN+N_WFC+N_FEAT)/256, 256, 0, stream>>>(
      qW,kW,vW,rW,qb,kb,vb,rb, ffnW, fcW, feature, WT_x, bcat, WT_ffn, WT_fc, feat_bf);

  knn_xyz_kernel<<<ROWS, 64, 0, stream>>>(xyz, base_xyz, idx0);
  rownorm_kernel<<<ROWS/256, 256, 0, stream>>>(feature, nrm);

  // per-batch feature-distance (frozen bit-exact) + wave-parallel top-k
  for (int b = 0; b < 4; ++b){
    const float* fb = feature + (size_t)b*NPTS*CIN;
    dist_feat_kernel<<<dim3(NPTS/32, NPTS/32), 256, 0, stream>>>(
        fb, nrm + (size_t)b*NPTS, Dbuf);
    topk_row_kernel<<<NPTS, 64, 0, stream>>>(Dbuf, idx1 + (size_t)b*NPTS*KNN);
  }

  // X[8192][2048] bf16 = feat_bf @ WT_x^T, both branches in one launch
  mfma_gemm<unsigned short><<<dim3(2048/64, ROWS/64, 1), 256, 0, stream>>>(
      feat_bf, WT_x, bcat, X_bf, 2048, CIN, 0, 0, 0, 0);

  // attention: both branches, one launch
  attn_kernel<<<dim3(ROWS/2, 2), 256, 0, stream>>>(X_bf, idx0, idx1, ctx_bf);

  // res BN stats (both branches)
  bnx_partial<<<dim3(32, 2), 256, 0, stream>>>(X_bf, partial);
  bn_final2<<<dim3(1, 2), 256, 0, stream>>>(partial, stats);          // slots 0,1

  // ffn GEMM: F_bf[i] = ctx_bf[i] @ ffnW_i + ffnb_i  (batched grid.z=2)
  mfma_gemm<unsigned short><<<dim3(COUT/64, ROWS/64, 2), 256, 0, stream>>>(
      ctx_bf, WT_ffn, ffnb, F_bf, COUT, COUT,
      (size_t)ROWS*COUT, (size_t)COUT*COUT, COUT, (size_t)ROWS*COUT);

  bnf_partial<<<dim3(32, 2), 256, 0, stream>>>(F_bf, partial);
  bn_final2<<<dim3(1, 2), 256, 0, stream>>>(partial, stats + 2*512);  // slots 2,3

  build_m_kernel<<<ROWS, 256, 0, stream>>>(X_bf, F_bf, stats,
      res_gamma, res_beta, ffn_gamma, ffn_beta, Mmat_bf);

  // fc: Y = Mmat @ fcW + fcb  (ctx region dead -> Y)
  mfma_gemm<float><<<dim3(COUT/64, ROWS/64, 1), 256, 0, stream>>>(
      Mmat_bf, WT_fc, fcb, Y, COUT, 512, 0, 0, 0, 0);

  bny_partial<<<32, 256, 0, stream>>>(Y, partial);
  bn_final2<<<dim3(1, 1), 256, 0, stream>>>(partial, stats + 4*512);  // slot 4

  final_kernel<<<ROWS, 256, 0, stream>>>(Y, stats + 4*512, fc_gamma, fc_beta, out);
}